// Round 17
// baseline (2694.724 us; speedup 1.0000x reference)
//
#include <hip/hip_runtime.h>
#include <stdint.h>

#define NPOINT 1024
#define NSAMPLE 32
#define NB 16
#define NN 4096
#define BN_EPS 1e-5
#define NPIX (NB*NPOINT*NSAMPLE)   // 524288 pixels (b,s,k)
#define NBLK 8192                  // fused_pass grid

// f32, no FMA contraction (FPS only — verified index-exact vs reference via out0).
__device__ __forceinline__ float sqdist3(float dx, float dy, float dz) {
  #pragma clang fp contract(off)
  float a = dx*dx; float b = dy*dy; float c = dz*dz;
  return (a + b) + c;
}

// ---------------- FPS: 256 thr x 16 pts, DPP wave-reduce, tree in-thread reduce --
#define DPP_COMBINE(CTRL)                                                     \
  {                                                                           \
    float ov = __int_as_float(__builtin_amdgcn_update_dpp(                    \
        __float_as_int(bv), __float_as_int(bv), (CTRL), 0xf, 0xf, false));    \
    int oj = __builtin_amdgcn_update_dpp(bj, bj, (CTRL), 0xf, 0xf, false);    \
    if (ov > bv || (ov == bv && oj < bj)) { bv = ov; bj = oj; }               \
  }

__global__ __launch_bounds__(256) void fps_kernel(
    const float* __restrict__ xyz, int* __restrict__ cents_g) {
  __shared__ __align__(16) float4 pos[NN];           // 64 KB
  __shared__ __align__(16) float rv[2][4];
  __shared__ __align__(16) int   rj[2][4];
  const int b = blockIdx.x;
  const int t = threadIdx.x;
  const float* base = xyz + (size_t)b * NN * 3;
  for (int i = t; i < NN; i += 256) {
    pos[i] = make_float4(base[3*i+0], base[3*i+1], base[3*i+2], 0.f);
  }
  __syncthreads();
  float px[16], py[16], pz[16], dist[16];
  #pragma unroll
  for (int i = 0; i < 16; i++) {
    float4 p = pos[i*256 + t];
    px[i] = p.x; py[i] = p.y; pz[i] = p.z;
    dist[i] = 1e10f;
  }
  const int lane = t & 63, wid = t >> 6;
  int far = 0;
  for (int it = 0; it < NPOINT; it++) {
    if (t == 0) cents_g[b*NPOINT + it] = far;   // carry BEFORE update (lax.scan)
    float4 c = pos[far];                        // single b128 broadcast
    // independent per-point updates (ILP), winners into a register tree
    float v[16]; int ji[16];
    #pragma unroll
    for (int i = 0; i < 16; i++) {
      float d = sqdist3(px[i]-c.x, py[i]-c.y, pz[i]-c.z);
      float nd = fminf(dist[i], d);
      dist[i] = nd;
      v[i] = nd; ji[i] = i*256 + t;
    }
    // 4-level lexicographic tree (max value, min index) — identical result to the
    // ascending strict-> serial scan
    #pragma unroll
    for (int s = 8; s > 0; s >>= 1)
      #pragma unroll
      for (int i = 0; i < s; i++) {
        if (v[i+s] > v[i] || (v[i+s] == v[i] && ji[i+s] < ji[i])) {
          v[i] = v[i+s]; ji[i] = ji[i+s];
        }
      }
    float bv = v[0]; int bj = ji[0];
    // DPP ladder: row_shr 1,2,4,8 then row_bcast 15,31 — lane 63 holds wave result
    DPP_COMBINE(0x111);
    DPP_COMBINE(0x112);
    DPP_COMBINE(0x114);
    DPP_COMBINE(0x118);
    DPP_COMBINE(0x142);
    DPP_COMBINE(0x143);
    const int p = it & 1;
    if (lane == 63) { rv[p][wid] = bv; rj[p][wid] = bj; }
    __syncthreads();
    float4 vv = *(const float4*)rv[p];
    int4   jv = *(const int4*)rj[p];
    float vb = vv.x; int jx = jv.x;
    if (vv.y > vb || (vv.y == vb && jv.y < jx)) { vb = vv.y; jx = jv.y; }
    if (vv.z > vb || (vv.z == vb && jv.z < jx)) { vb = vv.z; jx = jv.z; }
    if (vv.w > vb || (vv.w == vb && jv.w < jx)) { vb = vv.w; jx = jv.w; }
    far = jx;
  }
}

// ---------------- ball query: F64 distances (the proven discrete-exact fix) ------
__global__ __launch_bounds__(256) void ballquery_kernel(
    const float* __restrict__ xyz, const int* __restrict__ cents_g,
    int* __restrict__ idx) {
  const int w = blockIdx.x * 4 + (threadIdx.x >> 6);
  const int lane = threadIdx.x & 63;
  const int b = w >> 10;
  const double RR = 0.2 * 0.2;
  const int cj = cents_g[w] & (NN-1);
  const float* cptr = xyz + ((size_t)b * NN + cj) * 3;
  const double cx = (double)cptr[0], cy = (double)cptr[1], cz = (double)cptr[2];
  const double cn = cx*cx + cy*cy + cz*cz;
  const float* base = xyz + (size_t)b * NN * 3;
  int* out = idx + (size_t)w * NSAMPLE;
  int have = 0, firstj = 0;
  for (int j0 = 0; j0 < NN; j0 += 64) {
    int j = j0 + lane;
    double x = (double)base[3*j+0];
    double y = (double)base[3*j+1];
    double z = (double)base[3*j+2];
    double pn = x*x + y*y + z*z;
    double d = -2.0*(cx*x + cy*y + cz*z) + cn + pn;
    bool pass = !(d > RR);
    unsigned long long m = __ballot(pass);
    int cnt = __popcll(m);
    if (have == 0 && cnt > 0) firstj = j0 + (__ffsll((unsigned long long)m) - 1);
    if (pass) {
      int pos = have + __popcll(m & ((1ull << lane) - 1ull));
      if (pos < NSAMPLE) out[pos] = j;
    }
    have += cnt;
    if (have >= NSAMPLE) break;
  }
  for (int k = have + lane; k < NSAMPLE; k += 64) out[k] = firstj;
}

// ---------------- fused pass: NO ATOMICS — per-block f64 partials ---------------
template<int MODE>
__global__ __launch_bounds__(256) void fused_pass(
    const float* __restrict__ xyz, const float* __restrict__ points,
    const int* __restrict__ cents_g, const int* __restrict__ idx,
    const float* __restrict__ w1, const float* __restrict__ b1,
    const float* __restrict__ w2, const float* __restrict__ b2,
    const float* __restrict__ w3, const float* __restrict__ b3,
    const double* __restrict__ aff1, const double* __restrict__ aff2,
    double* __restrict__ partial, float* __restrict__ pmax, float* __restrict__ pmin) {
  __shared__ float wbuf[67*64];   // w1, then w2, then w3 halves
  __shared__ float xsm[67*68];    // gather in, then bn1 out, then bn2 out
  __shared__ float bsm[64];       // b1, then b3-half
  __shared__ float bsm2[64];      // b2
  __shared__ float sc1m[64], sh1m[64], sc2m[64], sh2m[64];
  const int t = threadIdx.x;
  const int pb = blockIdx.x * 64;
  const int tr = t & 15, tc = t >> 4;
  double* pout = partial + (size_t)blockIdx.x * 256;

  for (int ii = t; ii < 67*64; ii += 256) {
    int oc = ii & 63, cc = ii >> 6;
    wbuf[cc*64 + oc] = w1[oc*67 + cc];
  }
  if (t < 64) {
    bsm[t] = b1[t];
    if (MODE >= 2) { sc1m[t] = (float)aff1[t]; sh1m[t] = (float)aff1[128+t]; }
    if (MODE >= 3) { sc2m[t] = (float)aff2[t]; sh2m[t] = (float)aff2[128+t]; }
  }
  {
    const int pxl = t >> 2, q = t & 3;
    const int p = pb + pxl;
    const int bs = p >> 5;
    const int b  = p >> 15;
    const int j  = idx[p] & (NN-1);
    const float4* prow = (const float4*)(points + ((size_t)b * NN + j) * 64);
    #pragma unroll
    for (int u = 0; u < 4; u++) {
      float4 v = prow[q*4 + u];
      int c0 = 3 + q*16 + u*4;
      xsm[(c0+0)*68 + pxl] = v.x;
      xsm[(c0+1)*68 + pxl] = v.y;
      xsm[(c0+2)*68 + pxl] = v.z;
      xsm[(c0+3)*68 + pxl] = v.w;
    }
    if (q == 0) {
      const float* xr = xyz + ((size_t)b * NN + j) * 3;
      const int cj = cents_g[bs] & (NN-1);
      const float* ce = xyz + ((size_t)b * NN + cj) * 3;
      xsm[0*68 + pxl] = xr[0] - ce[0];
      xsm[1*68 + pxl] = xr[1] - ce[1];
      xsm[2*68 + pxl] = xr[2] - ce[2];
    }
  }
  __syncthreads();

  // ---- gemm1 (67 -> 64) f32 ----
  float acc[4][4] = {};
  for (int cc = 0; cc < 67; cc++) {
    float4 xv = *(const float4*)&xsm[cc*68 + 4*tr];
    float4 wv = *(const float4*)&wbuf[cc*64 + 4*tc];
    float xa[4] = {xv.x, xv.y, xv.z, xv.w};
    float wa[4] = {wv.x, wv.y, wv.z, wv.w};
    #pragma unroll
    for (int i = 0; i < 4; i++)
      #pragma unroll
      for (int jj = 0; jj < 4; jj++) acc[i][jj] += xa[i]*wa[jj];
  }
  if constexpr (MODE == 1) {
    double s1[4] = {0,0,0,0}, s2[4] = {0,0,0,0};
    #pragma unroll
    for (int jj = 0; jj < 4; jj++) {
      float bb = bsm[4*tc+jj];
      #pragma unroll
      for (int i = 0; i < 4; i++) {
        double yd = (double)(acc[i][jj] + bb);
        s1[jj] += yd; s2[jj] += yd*yd;
      }
    }
    #pragma unroll
    for (int off = 8; off > 0; off >>= 1)
      #pragma unroll
      for (int jj = 0; jj < 4; jj++) {
        s1[jj] += __shfl_down(s1[jj], off, 16);
        s2[jj] += __shfl_down(s2[jj], off, 16);
      }
    if (tr == 0)
      #pragma unroll
      for (int jj = 0; jj < 4; jj++) {
        pout[4*tc+jj]       = s1[jj];
        pout[128 + 4*tc+jj] = s2[jj];
      }
    return;
  }

  __syncthreads();
  #pragma unroll
  for (int jj = 0; jj < 4; jj++) {
    int oc = 4*tc + jj;
    float bb = bsm[oc], sc = sc1m[oc], sh = sh1m[oc];
    float r[4];
    #pragma unroll
    for (int i = 0; i < 4; i++) r[i] = fmaxf((acc[i][jj] + bb)*sc + sh, 0.f);
    *(float4*)&xsm[oc*68 + 4*tr] = make_float4(r[0], r[1], r[2], r[3]);
  }
  for (int ii = t; ii < 4096; ii += 256) {
    int oc = ii & 63, cc = ii >> 6;
    wbuf[cc*64 + oc] = w2[oc*64 + cc];
  }
  if (t < 64) bsm2[t] = b2[t];
  __syncthreads();

  // ---- gemm2 (64 -> 64) f32 ----
  float acc2[4][4] = {};
  for (int cc = 0; cc < 64; cc++) {
    float4 xv = *(const float4*)&xsm[cc*68 + 4*tr];
    float4 wv = *(const float4*)&wbuf[cc*64 + 4*tc];
    float xa[4] = {xv.x, xv.y, xv.z, xv.w};
    float wa[4] = {wv.x, wv.y, wv.z, wv.w};
    #pragma unroll
    for (int i = 0; i < 4; i++)
      #pragma unroll
      for (int jj = 0; jj < 4; jj++) acc2[i][jj] += xa[i]*wa[jj];
  }
  if constexpr (MODE == 2) {
    double s1[4] = {0,0,0,0}, s2[4] = {0,0,0,0};
    #pragma unroll
    for (int jj = 0; jj < 4; jj++) {
      float bb = bsm2[4*tc+jj];
      #pragma unroll
      for (int i = 0; i < 4; i++) {
        double yd = (double)(acc2[i][jj] + bb);
        s1[jj] += yd; s2[jj] += yd*yd;
      }
    }
    #pragma unroll
    for (int off = 8; off > 0; off >>= 1)
      #pragma unroll
      for (int jj = 0; jj < 4; jj++) {
        s1[jj] += __shfl_down(s1[jj], off, 16);
        s2[jj] += __shfl_down(s2[jj], off, 16);
      }
    if (tr == 0)
      #pragma unroll
      for (int jj = 0; jj < 4; jj++) {
        pout[4*tc+jj]       = s1[jj];
        pout[128 + 4*tc+jj] = s2[jj];
      }
    return;
  }

  if constexpr (MODE == 3) {
    __syncthreads();
    #pragma unroll
    for (int jj = 0; jj < 4; jj++) {
      int oc = 4*tc + jj;
      float bb = bsm2[oc], sc = sc2m[oc], sh = sh2m[oc];
      float r[4];
      #pragma unroll
      for (int i = 0; i < 4; i++) r[i] = fmaxf((acc2[i][jj] + bb)*sc + sh, 0.f);
      *(float4*)&xsm[oc*68 + 4*tr] = make_float4(r[0], r[1], r[2], r[3]);
    }
    for (int h = 0; h < 2; h++) {
      for (int ii = t; ii < 4096; ii += 256) {
        int oc = ii & 63, cc = ii >> 6;
        wbuf[cc*64 + oc] = w3[(h*64 + oc)*64 + cc];
      }
      if (t < 64) bsm[t] = b3[h*64 + t];
      __syncthreads();
      float acc3[4][4] = {};
      for (int cc = 0; cc < 64; cc++) {
        float4 xv = *(const float4*)&xsm[cc*68 + 4*tr];
        float4 wv = *(const float4*)&wbuf[cc*64 + 4*tc];
        float xa[4] = {xv.x, xv.y, xv.z, xv.w};
        float wa[4] = {wv.x, wv.y, wv.z, wv.w};
        #pragma unroll
        for (int i = 0; i < 4; i++)
          #pragma unroll
          for (int jj = 0; jj < 4; jj++) acc3[i][jj] += xa[i]*wa[jj];
      }
      double s1[4] = {0,0,0,0}, s2[4] = {0,0,0,0};
      float pmx[4], pmn[4];
      #pragma unroll
      for (int jj = 0; jj < 4; jj++) { pmx[jj] = -3.4e38f; pmn[jj] = 3.4e38f; }
      #pragma unroll
      for (int jj = 0; jj < 4; jj++) {
        float bb = bsm[4*tc+jj];
        #pragma unroll
        for (int i = 0; i < 4; i++) {
          float y = acc3[i][jj] + bb;
          double yd = (double)y;
          s1[jj] += yd; s2[jj] += yd*yd;
          pmx[jj] = fmaxf(pmx[jj], y); pmn[jj] = fminf(pmn[jj], y);
        }
      }
      #pragma unroll
      for (int off = 8; off > 0; off >>= 1)
        #pragma unroll
        for (int jj = 0; jj < 4; jj++) {
          s1[jj] += __shfl_down(s1[jj], off, 16);
          s2[jj] += __shfl_down(s2[jj], off, 16);
        }
      if (tr == 0)
        #pragma unroll
        for (int jj = 0; jj < 4; jj++) {
          pout[h*64 + 4*tc+jj]       = s1[jj];
          pout[128 + h*64 + 4*tc+jj] = s2[jj];
        }
      #pragma unroll
      for (int off = 4; off > 0; off >>= 1)
        #pragma unroll
        for (int jj = 0; jj < 4; jj++) {
          pmx[jj] = fmaxf(pmx[jj], __shfl_down(pmx[jj], off, 8));
          pmn[jj] = fminf(pmn[jj], __shfl_down(pmn[jj], off, 8));
        }
      if ((tr & 7) == 0) {
        int bs = (pb >> 5) + (tr >> 3);
        size_t ob = (size_t)bs*128 + h*64 + 4*tc;
        #pragma unroll
        for (int jj = 0; jj < 4; jj++) {
          pmax[ob + jj] = pmx[jj];
          pmin[ob + jj] = pmn[jj];
        }
      }
      __syncthreads();
    }
  }
}

// ---------------- reduce partials + compute affine -------------------------------
__global__ __launch_bounds__(256) void reduce_finalize_kernel(
    const double* __restrict__ partial,
    const float* __restrict__ g, const float* __restrict__ beta,
    double* __restrict__ aff) {
  __shared__ double sa1[4], sa2[4];
  const int c = blockIdx.x;
  const int t = threadIdx.x;
  double a1 = 0.0, a2 = 0.0;
  for (int blk = t; blk < NBLK; blk += 256) {
    a1 += partial[(size_t)blk*256 + c];
    a2 += partial[(size_t)blk*256 + 128 + c];
  }
  #pragma unroll
  for (int off = 32; off > 0; off >>= 1) {
    a1 += __shfl_down(a1, off);
    a2 += __shfl_down(a2, off);
  }
  const int lane = t & 63, wid = t >> 6;
  if (lane == 0) { sa1[wid] = a1; sa2[wid] = a2; }
  __syncthreads();
  if (t == 0) {
    double s1 = sa1[0] + sa1[1] + sa1[2] + sa1[3];
    double s2 = sa2[0] + sa2[1] + sa2[2] + sa2[3];
    const double invN = 1.0 / (double)NPIX;
    double mean = s1 * invN;
    double var  = s2 * invN - mean*mean;
    var = var > 0.0 ? var : 0.0;
    double r  = 1.0 / sqrt(var + BN_EPS);
    double sc = (double)g[c] * r;
    aff[c]       = sc;
    aff[128 + c] = (double)beta[c] - mean*sc;
  }
}

// ---------------- epilogue: bn3+relu on pooled extremum (monotone trick) ---------
__global__ __launch_bounds__(256) void out_kernel(
    const float* __restrict__ pmax, const float* __restrict__ pmin,
    const double* __restrict__ aff3, float* __restrict__ out_np) {
  int i = blockIdx.x * 256 + threadIdx.x;   // [0, 2097152)
  int oc = i & 127;
  double sc = aff3[oc], sh = aff3[128+oc];
  double v = (sc >= 0.0) ? (double)pmax[i] : (double)pmin[i];
  double y = v*sc + sh;
  out_np[i] = (float)(y > 0.0 ? y : 0.0);
}

// ---------------- sole writer of new_xyz ------------------------------------------
__global__ __launch_bounds__(1024) void write_newxyz_kernel(
    const float* __restrict__ xyz, const int* __restrict__ cents_g,
    float* __restrict__ out) {
  int i = blockIdx.x * 1024 + threadIdx.x;    // [0, 16384)
  int b = i >> 10;
  int j = cents_g[i] & (NN-1);
  const float* src = xyz + ((size_t)b * NN + j) * 3;
  size_t o = (size_t)i * 3;
  out[o+0] = src[0];
  out[o+1] = src[1];
  out[o+2] = src[2];
}

extern "C" void kernel_launch(void* const* d_in, const int* in_sizes, int n_in,
                              void* d_out, int out_size, void* d_ws, size_t ws_size,
                              hipStream_t stream) {
  const float* xyz    = (const float*)d_in[0];
  const float* points = (const float*)d_in[1];
  const float* w1  = (const float*)d_in[2];
  const float* b1  = (const float*)d_in[3];
  const float* g1  = (const float*)d_in[4];
  const float* be1 = (const float*)d_in[5];
  const float* w2  = (const float*)d_in[6];
  const float* b2  = (const float*)d_in[7];
  const float* g2  = (const float*)d_in[8];
  const float* be2 = (const float*)d_in[9];
  const float* w3  = (const float*)d_in[10];
  const float* b3  = (const float*)d_in[11];
  const float* g3  = (const float*)d_in[12];
  const float* be3 = (const float*)d_in[13];

  // workspace ~36 MB (known safe: 86 MB ran clean in R2)
  char* ws = (char*)d_ws;
  double* aff     = (double*)(ws + 8192);      // 768 f64
  int*    cents   = (int*)  (ws + 16384);      // 16384 i32
  int*    idx     = (int*)  (ws + 81920);      // 524288 i32
  float*  pmax    = (float*)(ws + 2179072);    // 2097152 f32
  float*  pmin    = (float*)(ws + 10567680);   // 2097152 f32
  double* partial = (double*)(ws + 18956288);  // 8192*256 f64 = 16 MB
  float* out_xyz = (float*)d_out;                          // f32 new_xyz
  float* out_np  = (float*)d_out + (size_t)NB*NPOINT*3;    // f32 new_points

  fps_kernel        <<<16,   256, 0, stream>>>(xyz, cents);
  ballquery_kernel  <<<4096, 256, 0, stream>>>(xyz, cents, idx);
  fused_pass<1>     <<<NBLK, 256, 0, stream>>>(xyz, points, cents, idx, w1,b1,w2,b2,w3,b3,
                                               aff, aff+256, partial, pmax, pmin);
  reduce_finalize_kernel<<<64, 256, 0, stream>>>(partial, g1, be1, aff);
  fused_pass<2>     <<<NBLK, 256, 0, stream>>>(xyz, points, cents, idx, w1,b1,w2,b2,w3,b3,
                                               aff, aff+256, partial, pmax, pmin);
  reduce_finalize_kernel<<<64, 256, 0, stream>>>(partial, g2, be2, aff+256);
  fused_pass<3>     <<<NBLK, 256, 0, stream>>>(xyz, points, cents, idx, w1,b1,w2,b2,w3,b3,
                                               aff, aff+256, partial, pmax, pmin);
  reduce_finalize_kernel<<<128, 256, 0, stream>>>(partial, g3, be3, aff+512);
  out_kernel        <<<NBLK, 256, 0, stream>>>(pmax, pmin, aff+512, out_np);
  write_newxyz_kernel<<<16, 1024, 0, stream>>>(xyz, cents, out_xyz);
}

// Round 19
// 1742.122 us; speedup vs baseline: 1.5468x; 1.5468x over previous
//
#include <hip/hip_runtime.h>
#include <stdint.h>

#define NPOINT 1024
#define NSAMPLE 32
#define NB 16
#define NN 4096
#define BN_EPS 1e-5
#define NPIX (NB*NPOINT*NSAMPLE)   // 524288 pixels (b,s,k)
#define NBLK 8192                  // fused_pass grid

// f32, no FMA contraction (FPS only — verified index-exact vs reference via out0).
__device__ __forceinline__ float sqdist3(float dx, float dy, float dz) {
  #pragma clang fp contract(off)
  float a = dx*dx; float b = dy*dy; float c = dz*dz;
  return (a + b) + c;
}

// ---------------- FPS: 256 thr x 16 pts, DPP wave-reduce (R15 proven: 931us) ----
#define DPP_COMBINE(CTRL)                                                     \
  {                                                                           \
    float ov = __int_as_float(__builtin_amdgcn_update_dpp(                    \
        __float_as_int(bv), __float_as_int(bv), (CTRL), 0xf, 0xf, false));    \
    int oj = __builtin_amdgcn_update_dpp(bj, bj, (CTRL), 0xf, 0xf, false);    \
    if (ov > bv || (ov == bv && oj < bj)) { bv = ov; bj = oj; }               \
  }

__global__ __launch_bounds__(256) void fps_kernel(
    const float* __restrict__ xyz, int* __restrict__ cents_g) {
  __shared__ __align__(16) float4 pos[NN];           // 64 KB
  __shared__ __align__(16) float rv[2][4];
  __shared__ __align__(16) int   rj[2][4];
  const int b = blockIdx.x;
  const int t = threadIdx.x;
  const float* base = xyz + (size_t)b * NN * 3;
  for (int i = t; i < NN; i += 256) {
    pos[i] = make_float4(base[3*i+0], base[3*i+1], base[3*i+2], 0.f);
  }
  __syncthreads();
  float px[16], py[16], pz[16], dist[16];
  #pragma unroll
  for (int i = 0; i < 16; i++) {
    float4 p = pos[i*256 + t];
    px[i] = p.x; py[i] = p.y; pz[i] = p.z;
    dist[i] = 1e10f;
  }
  const int lane = t & 63, wid = t >> 6;
  int far = 0;
  for (int it = 0; it < NPOINT; it++) {
    if (t == 0) cents_g[b*NPOINT + it] = far;   // carry BEFORE update (lax.scan)
    float4 c = pos[far];                        // single b128 broadcast
    float bv = -1.0f; int bj = 0x7fffffff;
    #pragma unroll
    for (int i = 0; i < 16; i++) {
      float d = sqdist3(px[i]-c.x, py[i]-c.y, pz[i]-c.z);
      float nd = fminf(dist[i], d);
      dist[i] = nd;
      int j = i*256 + t;
      if (nd > bv) { bv = nd; bj = j; }   // ascending j within thread: > keeps first
    }
    // DPP ladder: row_shr 1,2,4,8 then row_bcast 15,31 — lane 63 holds wave result
    DPP_COMBINE(0x111);
    DPP_COMBINE(0x112);
    DPP_COMBINE(0x114);
    DPP_COMBINE(0x118);
    DPP_COMBINE(0x142);
    DPP_COMBINE(0x143);
    const int p = it & 1;
    if (lane == 63) { rv[p][wid] = bv; rj[p][wid] = bj; }
    __syncthreads();
    float4 vv = *(const float4*)rv[p];
    int4   jv = *(const int4*)rj[p];
    float v = vv.x; int jx = jv.x;
    if (vv.y > v || (vv.y == v && jv.y < jx)) { v = vv.y; jx = jv.y; }
    if (vv.z > v || (vv.z == v && jv.z < jx)) { v = vv.z; jx = jv.z; }
    if (vv.w > v || (vv.w == v && jv.w < jx)) { v = vv.w; jx = jv.w; }
    far = jx;
  }
}

// ---------------- ball query: F64 distances (the proven discrete-exact fix) ------
__global__ __launch_bounds__(256) void ballquery_kernel(
    const float* __restrict__ xyz, const int* __restrict__ cents_g,
    int* __restrict__ idx) {
  const int w = blockIdx.x * 4 + (threadIdx.x >> 6);
  const int lane = threadIdx.x & 63;
  const int b = w >> 10;
  const double RR = 0.2 * 0.2;
  const int cj = cents_g[w] & (NN-1);
  const float* cptr = xyz + ((size_t)b * NN + cj) * 3;
  const double cx = (double)cptr[0], cy = (double)cptr[1], cz = (double)cptr[2];
  const double cn = cx*cx + cy*cy + cz*cz;
  const float* base = xyz + (size_t)b * NN * 3;
  int* out = idx + (size_t)w * NSAMPLE;
  int have = 0, firstj = 0;
  for (int j0 = 0; j0 < NN; j0 += 64) {
    int j = j0 + lane;
    double x = (double)base[3*j+0];
    double y = (double)base[3*j+1];
    double z = (double)base[3*j+2];
    double pn = x*x + y*y + z*z;
    double d = -2.0*(cx*x + cy*y + cz*z) + cn + pn;
    bool pass = !(d > RR);
    unsigned long long m = __ballot(pass);
    int cnt = __popcll(m);
    if (have == 0 && cnt > 0) firstj = j0 + (__ffsll((unsigned long long)m) - 1);
    if (pass) {
      int pos = have + __popcll(m & ((1ull << lane) - 1ull));
      if (pos < NSAMPLE) out[pos] = j;
    }
    have += cnt;
    if (have >= NSAMPLE) break;
  }
  for (int k = have + lane; k < NSAMPLE; k += 64) out[k] = firstj;
}

// ---------------- fused pass: NO ATOMICS — per-block f64 partials ---------------
template<int MODE>
__global__ __launch_bounds__(256) void fused_pass(
    const float* __restrict__ xyz, const float* __restrict__ points,
    const int* __restrict__ cents_g, const int* __restrict__ idx,
    const float* __restrict__ w1, const float* __restrict__ b1,
    const float* __restrict__ w2, const float* __restrict__ b2,
    const float* __restrict__ w3, const float* __restrict__ b3,
    const double* __restrict__ aff1, const double* __restrict__ aff2,
    double* __restrict__ partial, float* __restrict__ pmax, float* __restrict__ pmin) {
  __shared__ float wbuf[67*64];   // w1, then w2, then w3 halves
  __shared__ float xsm[67*68];    // gather in, then bn1 out, then bn2 out
  __shared__ float bsm[64];       // b1, then b3-half
  __shared__ float bsm2[64];      // b2
  __shared__ float sc1m[64], sh1m[64], sc2m[64], sh2m[64];
  const int t = threadIdx.x;
  const int pb = blockIdx.x * 64;
  const int tr = t & 15, tc = t >> 4;
  double* pout = partial + (size_t)blockIdx.x * 256;

  for (int ii = t; ii < 67*64; ii += 256) {
    int oc = ii & 63, cc = ii >> 6;
    wbuf[cc*64 + oc] = w1[oc*67 + cc];
  }
  if (t < 64) {
    bsm[t] = b1[t];
    if (MODE >= 2) { sc1m[t] = (float)aff1[t]; sh1m[t] = (float)aff1[128+t]; }
    if (MODE >= 3) { sc2m[t] = (float)aff2[t]; sh2m[t] = (float)aff2[128+t]; }
  }
  {
    const int pxl = t >> 2, q = t & 3;
    const int p = pb + pxl;
    const int bs = p >> 5;
    const int b  = p >> 15;
    const int j  = idx[p] & (NN-1);
    const float4* prow = (const float4*)(points + ((size_t)b * NN + j) * 64);
    #pragma unroll
    for (int u = 0; u < 4; u++) {
      float4 v = prow[q*4 + u];
      int c0 = 3 + q*16 + u*4;
      xsm[(c0+0)*68 + pxl] = v.x;
      xsm[(c0+1)*68 + pxl] = v.y;
      xsm[(c0+2)*68 + pxl] = v.z;
      xsm[(c0+3)*68 + pxl] = v.w;
    }
    if (q == 0) {
      const float* xr = xyz + ((size_t)b * NN + j) * 3;
      const int cj = cents_g[bs] & (NN-1);
      const float* ce = xyz + ((size_t)b * NN + cj) * 3;
      xsm[0*68 + pxl] = xr[0] - ce[0];
      xsm[1*68 + pxl] = xr[1] - ce[1];
      xsm[2*68 + pxl] = xr[2] - ce[2];
    }
  }
  __syncthreads();

  // ---- gemm1 (67 -> 64) f32 ----
  float acc[4][4] = {};
  for (int cc = 0; cc < 67; cc++) {
    float4 xv = *(const float4*)&xsm[cc*68 + 4*tr];
    float4 wv = *(const float4*)&wbuf[cc*64 + 4*tc];
    float xa[4] = {xv.x, xv.y, xv.z, xv.w};
    float wa[4] = {wv.x, wv.y, wv.z, wv.w};
    #pragma unroll
    for (int i = 0; i < 4; i++)
      #pragma unroll
      for (int jj = 0; jj < 4; jj++) acc[i][jj] += xa[i]*wa[jj];
  }
  if constexpr (MODE == 1) {
    double s1[4] = {0,0,0,0}, s2[4] = {0,0,0,0};
    #pragma unroll
    for (int jj = 0; jj < 4; jj++) {
      float bb = bsm[4*tc+jj];
      #pragma unroll
      for (int i = 0; i < 4; i++) {
        double yd = (double)(acc[i][jj] + bb);
        s1[jj] += yd; s2[jj] += yd*yd;
      }
    }
    #pragma unroll
    for (int off = 8; off > 0; off >>= 1)
      #pragma unroll
      for (int jj = 0; jj < 4; jj++) {
        s1[jj] += __shfl_down(s1[jj], off, 16);
        s2[jj] += __shfl_down(s2[jj], off, 16);
      }
    if (tr == 0)
      #pragma unroll
      for (int jj = 0; jj < 4; jj++) {
        pout[4*tc+jj]       = s1[jj];
        pout[128 + 4*tc+jj] = s2[jj];
      }
    return;
  }

  __syncthreads();
  #pragma unroll
  for (int jj = 0; jj < 4; jj++) {
    int oc = 4*tc + jj;
    float bb = bsm[oc], sc = sc1m[oc], sh = sh1m[oc];
    float r[4];
    #pragma unroll
    for (int i = 0; i < 4; i++) r[i] = fmaxf((acc[i][jj] + bb)*sc + sh, 0.f);
    *(float4*)&xsm[oc*68 + 4*tr] = make_float4(r[0], r[1], r[2], r[3]);
  }
  for (int ii = t; ii < 4096; ii += 256) {
    int oc = ii & 63, cc = ii >> 6;
    wbuf[cc*64 + oc] = w2[oc*64 + cc];
  }
  if (t < 64) bsm2[t] = b2[t];
  __syncthreads();

  // ---- gemm2 (64 -> 64) f32 ----
  float acc2[4][4] = {};
  for (int cc = 0; cc < 64; cc++) {
    float4 xv = *(const float4*)&xsm[cc*68 + 4*tr];
    float4 wv = *(const float4*)&wbuf[cc*64 + 4*tc];
    float xa[4] = {xv.x, xv.y, xv.z, xv.w};
    float wa[4] = {wv.x, wv.y, wv.z, wv.w};
    #pragma unroll
    for (int i = 0; i < 4; i++)
      #pragma unroll
      for (int jj = 0; jj < 4; jj++) acc2[i][jj] += xa[i]*wa[jj];
  }
  if constexpr (MODE == 2) {
    double s1[4] = {0,0,0,0}, s2[4] = {0,0,0,0};
    #pragma unroll
    for (int jj = 0; jj < 4; jj++) {
      float bb = bsm2[4*tc+jj];
      #pragma unroll
      for (int i = 0; i < 4; i++) {
        double yd = (double)(acc2[i][jj] + bb);
        s1[jj] += yd; s2[jj] += yd*yd;
      }
    }
    #pragma unroll
    for (int off = 8; off > 0; off >>= 1)
      #pragma unroll
      for (int jj = 0; jj < 4; jj++) {
        s1[jj] += __shfl_down(s1[jj], off, 16);
        s2[jj] += __shfl_down(s2[jj], off, 16);
      }
    if (tr == 0)
      #pragma unroll
      for (int jj = 0; jj < 4; jj++) {
        pout[4*tc+jj]       = s1[jj];
        pout[128 + 4*tc+jj] = s2[jj];
      }
    return;
  }

  if constexpr (MODE == 3) {
    __syncthreads();
    #pragma unroll
    for (int jj = 0; jj < 4; jj++) {
      int oc = 4*tc + jj;
      float bb = bsm2[oc], sc = sc2m[oc], sh = sh2m[oc];
      float r[4];
      #pragma unroll
      for (int i = 0; i < 4; i++) r[i] = fmaxf((acc2[i][jj] + bb)*sc + sh, 0.f);
      *(float4*)&xsm[oc*68 + 4*tr] = make_float4(r[0], r[1], r[2], r[3]);
    }
    for (int h = 0; h < 2; h++) {
      for (int ii = t; ii < 4096; ii += 256) {
        int oc = ii & 63, cc = ii >> 6;
        wbuf[cc*64 + oc] = w3[(h*64 + oc)*64 + cc];
      }
      if (t < 64) bsm[t] = b3[h*64 + t];
      __syncthreads();
      float acc3[4][4] = {};
      for (int cc = 0; cc < 64; cc++) {
        float4 xv = *(const float4*)&xsm[cc*68 + 4*tr];
        float4 wv = *(const float4*)&wbuf[cc*64 + 4*tc];
        float xa[4] = {xv.x, xv.y, xv.z, xv.w};
        float wa[4] = {wv.x, wv.y, wv.z, wv.w};
        #pragma unroll
        for (int i = 0; i < 4; i++)
          #pragma unroll
          for (int jj = 0; jj < 4; jj++) acc3[i][jj] += xa[i]*wa[jj];
      }
      double s1[4] = {0,0,0,0}, s2[4] = {0,0,0,0};
      float pmx[4], pmn[4];
      #pragma unroll
      for (int jj = 0; jj < 4; jj++) { pmx[jj] = -3.4e38f; pmn[jj] = 3.4e38f; }
      #pragma unroll
      for (int jj = 0; jj < 4; jj++) {
        float bb = bsm[4*tc+jj];
        #pragma unroll
        for (int i = 0; i < 4; i++) {
          float y = acc3[i][jj] + bb;
          double yd = (double)y;
          s1[jj] += yd; s2[jj] += yd*yd;
          pmx[jj] = fmaxf(pmx[jj], y); pmn[jj] = fminf(pmn[jj], y);
        }
      }
      #pragma unroll
      for (int off = 8; off > 0; off >>= 1)
        #pragma unroll
        for (int jj = 0; jj < 4; jj++) {
          s1[jj] += __shfl_down(s1[jj], off, 16);
          s2[jj] += __shfl_down(s2[jj], off, 16);
        }
      if (tr == 0)
        #pragma unroll
        for (int jj = 0; jj < 4; jj++) {
          pout[h*64 + 4*tc+jj]       = s1[jj];
          pout[128 + h*64 + 4*tc+jj] = s2[jj];
        }
      #pragma unroll
      for (int off = 4; off > 0; off >>= 1)
        #pragma unroll
        for (int jj = 0; jj < 4; jj++) {
          pmx[jj] = fmaxf(pmx[jj], __shfl_down(pmx[jj], off, 8));
          pmn[jj] = fminf(pmn[jj], __shfl_down(pmn[jj], off, 8));
        }
      if ((tr & 7) == 0) {
        int bs = (pb >> 5) + (tr >> 3);
        size_t ob = (size_t)bs*128 + h*64 + 4*tc;
        #pragma unroll
        for (int jj = 0; jj < 4; jj++) {
          pmax[ob + jj] = pmx[jj];
          pmin[ob + jj] = pmn[jj];
        }
      }
      __syncthreads();
    }
  }
}

// ---------------- reduce partials + compute affine -------------------------------
__global__ __launch_bounds__(256) void reduce_finalize_kernel(
    const double* __restrict__ partial,
    const float* __restrict__ g, const float* __restrict__ beta,
    double* __restrict__ aff) {
  __shared__ double sa1[4], sa2[4];
  const int c = blockIdx.x;
  const int t = threadIdx.x;
  double a1 = 0.0, a2 = 0.0;
  for (int blk = t; blk < NBLK; blk += 256) {
    a1 += partial[(size_t)blk*256 + c];
    a2 += partial[(size_t)blk*256 + 128 + c];
  }
  #pragma unroll
  for (int off = 32; off > 0; off >>= 1) {
    a1 += __shfl_down(a1, off);
    a2 += __shfl_down(a2, off);
  }
  const int lane = t & 63, wid = t >> 6;
  if (lane == 0) { sa1[wid] = a1; sa2[wid] = a2; }
  __syncthreads();
  if (t == 0) {
    double s1 = sa1[0] + sa1[1] + sa1[2] + sa1[3];
    double s2 = sa2[0] + sa2[1] + sa2[2] + sa2[3];
    const double invN = 1.0 / (double)NPIX;
    double mean = s1 * invN;
    double var  = s2 * invN - mean*mean;
    var = var > 0.0 ? var : 0.0;
    double r  = 1.0 / sqrt(var + BN_EPS);
    double sc = (double)g[c] * r;
    aff[c]       = sc;
    aff[128 + c] = (double)beta[c] - mean*sc;
  }
}

// ---------------- epilogue: bn3+relu on pooled extremum (monotone trick) ---------
__global__ __launch_bounds__(256) void out_kernel(
    const float* __restrict__ pmax, const float* __restrict__ pmin,
    const double* __restrict__ aff3, float* __restrict__ out_np) {
  int i = blockIdx.x * 256 + threadIdx.x;   // [0, 2097152)
  int oc = i & 127;
  double sc = aff3[oc], sh = aff3[128+oc];
  double v = (sc >= 0.0) ? (double)pmax[i] : (double)pmin[i];
  double y = v*sc + sh;
  out_np[i] = (float)(y > 0.0 ? y : 0.0);
}

// ---------------- sole writer of new_xyz ------------------------------------------
__global__ __launch_bounds__(1024) void write_newxyz_kernel(
    const float* __restrict__ xyz, const int* __restrict__ cents_g,
    float* __restrict__ out) {
  int i = blockIdx.x * 1024 + threadIdx.x;    // [0, 16384)
  int b = i >> 10;
  int j = cents_g[i] & (NN-1);
  const float* src = xyz + ((size_t)b * NN + j) * 3;
  size_t o = (size_t)i * 3;
  out[o+0] = src[0];
  out[o+1] = src[1];
  out[o+2] = src[2];
}

extern "C" void kernel_launch(void* const* d_in, const int* in_sizes, int n_in,
                              void* d_out, int out_size, void* d_ws, size_t ws_size,
                              hipStream_t stream) {
  const float* xyz    = (const float*)d_in[0];
  const float* points = (const float*)d_in[1];
  const float* w1  = (const float*)d_in[2];
  const float* b1  = (const float*)d_in[3];
  const float* g1  = (const float*)d_in[4];
  const float* be1 = (const float*)d_in[5];
  const float* w2  = (const float*)d_in[6];
  const float* b2  = (const float*)d_in[7];
  const float* g2  = (const float*)d_in[8];
  const float* be2 = (const float*)d_in[9];
  const float* w3  = (const float*)d_in[10];
  const float* b3  = (const float*)d_in[11];
  const float* g3  = (const float*)d_in[12];
  const float* be3 = (const float*)d_in[13];

  // workspace ~36 MB (known safe: 86 MB ran clean in R2)
  char* ws = (char*)d_ws;
  double* aff     = (double*)(ws + 8192);      // 768 f64
  int*    cents   = (int*)  (ws + 16384);      // 16384 i32
  int*    idx     = (int*)  (ws + 81920);      // 524288 i32
  float*  pmax    = (float*)(ws + 2179072);    // 2097152 f32
  float*  pmin    = (float*)(ws + 10567680);   // 2097152 f32
  double* partial = (double*)(ws + 18956288);  // 8192*256 f64 = 16 MB
  float* out_xyz = (float*)d_out;                          // f32 new_xyz
  float* out_np  = (float*)d_out + (size_t)NB*NPOINT*3;    // f32 new_points

  fps_kernel        <<<16,   256, 0, stream>>>(xyz, cents);
  ballquery_kernel  <<<4096, 256, 0, stream>>>(xyz, cents, idx);
  fused_pass<1>     <<<NBLK, 256, 0, stream>>>(xyz, points, cents, idx, w1,b1,w2,b2,w3,b3,
                                               aff, aff+256, partial, pmax, pmin);
  reduce_finalize_kernel<<<64, 256, 0, stream>>>(partial, g1, be1, aff);
  fused_pass<2>     <<<NBLK, 256, 0, stream>>>(xyz, points, cents, idx, w1,b1,w2,b2,w3,b3,
                                               aff, aff+256, partial, pmax, pmin);
  reduce_finalize_kernel<<<64, 256, 0, stream>>>(partial, g2, be2, aff+256);
  fused_pass<3>     <<<NBLK, 256, 0, stream>>>(xyz, points, cents, idx, w1,b1,w2,b2,w3,b3,
                                               aff, aff+256, partial, pmax, pmin);
  reduce_finalize_kernel<<<128, 256, 0, stream>>>(partial, g3, be3, aff+512);
  out_kernel        <<<NBLK, 256, 0, stream>>>(pmax, pmin, aff+512, out_np);
  write_newxyz_kernel<<<16, 1024, 0, stream>>>(xyz, cents, out_xyz);
}

// Round 20
// 1702.668 us; speedup vs baseline: 1.5826x; 1.0232x over previous
//
#include <hip/hip_runtime.h>
#include <stdint.h>

#define NPOINT 1024
#define NSAMPLE 32
#define NB 16
#define NN 4096
#define BN_EPS 1e-5
#define NPIX (NB*NPOINT*NSAMPLE)   // 524288 pixels (b,s,k)
#define NBLK 8192                  // fused_pass grid

// f32, no FMA contraction (FPS only — verified index-exact vs reference via out0).
__device__ __forceinline__ float sqdist3(float dx, float dy, float dz) {
  #pragma clang fp contract(off)
  float a = dx*dx; float b = dy*dy; float c = dz*dz;
  return (a + b) + c;
}

// ---------------- FPS: 256 thr x 16 pts, DPP wave-reduce, LDS cents buffer ------
#define DPP_COMBINE(CTRL)                                                     \
  {                                                                           \
    float ov = __int_as_float(__builtin_amdgcn_update_dpp(                    \
        __float_as_int(bv), __float_as_int(bv), (CTRL), 0xf, 0xf, false));    \
    int oj = __builtin_amdgcn_update_dpp(bj, bj, (CTRL), 0xf, 0xf, false);    \
    if (ov > bv || (ov == bv && oj < bj)) { bv = ov; bj = oj; }               \
  }

__global__ __launch_bounds__(256) void fps_kernel(
    const float* __restrict__ xyz, int* __restrict__ cents_g) {
  __shared__ __align__(16) float4 pos[NN];           // 64 KB
  __shared__ __align__(16) float rv[2][4];
  __shared__ __align__(16) int   rj[2][4];
  __shared__ int cents_l[NPOINT];                    // 4 KB — no vmcnt at barrier
  const int b = blockIdx.x;
  const int t = threadIdx.x;
  const float* base = xyz + (size_t)b * NN * 3;
  for (int i = t; i < NN; i += 256) {
    pos[i] = make_float4(base[3*i+0], base[3*i+1], base[3*i+2], 0.f);
  }
  __syncthreads();
  float px[16], py[16], pz[16], dist[16];
  #pragma unroll
  for (int i = 0; i < 16; i++) {
    float4 p = pos[i*256 + t];
    px[i] = p.x; py[i] = p.y; pz[i] = p.z;
    dist[i] = 1e10f;
  }
  const int lane = t & 63, wid = t >> 6;
  int far = 0;
  for (int it = 0; it < NPOINT; it++) {
    if (t == 0) cents_l[it] = far;              // LDS only (carry BEFORE update)
    float4 c = pos[far];                        // single b128 broadcast
    float bv = -1.0f; int bj = 0x7fffffff;
    #pragma unroll
    for (int i = 0; i < 16; i++) {
      float d = sqdist3(px[i]-c.x, py[i]-c.y, pz[i]-c.z);
      float nd = fminf(dist[i], d);
      dist[i] = nd;
      int j = i*256 + t;
      if (nd > bv) { bv = nd; bj = j; }   // ascending j within thread: > keeps first
    }
    // DPP ladder: row_shr 1,2,4,8 then row_bcast 15,31 — lane 63 holds wave result
    DPP_COMBINE(0x111);
    DPP_COMBINE(0x112);
    DPP_COMBINE(0x114);
    DPP_COMBINE(0x118);
    DPP_COMBINE(0x142);
    DPP_COMBINE(0x143);
    const int p = it & 1;
    if (lane == 63) { rv[p][wid] = bv; rj[p][wid] = bj; }
    __syncthreads();
    float4 vv = *(const float4*)rv[p];
    int4   jv = *(const int4*)rj[p];
    float v = vv.x; int jx = jv.x;
    if (vv.y > v || (vv.y == v && jv.y < jx)) { v = vv.y; jx = jv.y; }
    if (vv.z > v || (vv.z == v && jv.z < jx)) { v = vv.z; jx = jv.z; }
    if (vv.w > v || (vv.w == v && jv.w < jx)) { v = vv.w; jx = jv.w; }
    far = jx;
  }
  __syncthreads();
  for (int i = t; i < NPOINT; i += 256) cents_g[b*NPOINT + i] = cents_l[i];
}

// ---------------- ball query: F64 distances (the proven discrete-exact fix) ------
__global__ __launch_bounds__(256) void ballquery_kernel(
    const float* __restrict__ xyz, const int* __restrict__ cents_g,
    int* __restrict__ idx) {
  const int w = blockIdx.x * 4 + (threadIdx.x >> 6);
  const int lane = threadIdx.x & 63;
  const int b = w >> 10;
  const double RR = 0.2 * 0.2;
  const int cj = cents_g[w] & (NN-1);
  const float* cptr = xyz + ((size_t)b * NN + cj) * 3;
  const double cx = (double)cptr[0], cy = (double)cptr[1], cz = (double)cptr[2];
  const double cn = cx*cx + cy*cy + cz*cz;
  const float* base = xyz + (size_t)b * NN * 3;
  int* out = idx + (size_t)w * NSAMPLE;
  int have = 0, firstj = 0;
  for (int j0 = 0; j0 < NN; j0 += 64) {
    int j = j0 + lane;
    double x = (double)base[3*j+0];
    double y = (double)base[3*j+1];
    double z = (double)base[3*j+2];
    double pn = x*x + y*y + z*z;
    double d = -2.0*(cx*x + cy*y + cz*z) + cn + pn;
    bool pass = !(d > RR);
    unsigned long long m = __ballot(pass);
    int cnt = __popcll(m);
    if (have == 0 && cnt > 0) firstj = j0 + (__ffsll((unsigned long long)m) - 1);
    if (pass) {
      int pos = have + __popcll(m & ((1ull << lane) - 1ull));
      if (pos < NSAMPLE) out[pos] = j;
    }
    have += cnt;
    if (have >= NSAMPLE) break;
  }
  for (int k = have + lane; k < NSAMPLE; k += 64) out[k] = firstj;
}

// ---------------- fused pass: NO ATOMICS — per-block f64 partials ---------------
template<int MODE>
__global__ __launch_bounds__(256) void fused_pass(
    const float* __restrict__ xyz, const float* __restrict__ points,
    const int* __restrict__ cents_g, const int* __restrict__ idx,
    const float* __restrict__ w1, const float* __restrict__ b1,
    const float* __restrict__ w2, const float* __restrict__ b2,
    const float* __restrict__ w3, const float* __restrict__ b3,
    const double* __restrict__ aff1, const double* __restrict__ aff2,
    double* __restrict__ partial, float* __restrict__ pmax, float* __restrict__ pmin) {
  __shared__ float wbuf[67*64];   // w1, then w2, then w3 halves
  __shared__ float xsm[67*68];    // gather in, then bn1 out, then bn2 out
  __shared__ float bsm[64];       // b1, then b3-half
  __shared__ float bsm2[64];      // b2
  __shared__ float sc1m[64], sh1m[64], sc2m[64], sh2m[64];
  const int t = threadIdx.x;
  const int pb = blockIdx.x * 64;
  const int tr = t & 15, tc = t >> 4;
  double* pout = partial + (size_t)blockIdx.x * 256;

  for (int ii = t; ii < 67*64; ii += 256) {
    int oc = ii & 63, cc = ii >> 6;
    wbuf[cc*64 + oc] = w1[oc*67 + cc];
  }
  if (t < 64) {
    bsm[t] = b1[t];
    if (MODE >= 2) { sc1m[t] = (float)aff1[t]; sh1m[t] = (float)aff1[128+t]; }
    if (MODE >= 3) { sc2m[t] = (float)aff2[t]; sh2m[t] = (float)aff2[128+t]; }
  }
  {
    const int pxl = t >> 2, q = t & 3;
    const int p = pb + pxl;
    const int bs = p >> 5;
    const int b  = p >> 15;
    const int j  = idx[p] & (NN-1);
    const float4* prow = (const float4*)(points + ((size_t)b * NN + j) * 64);
    #pragma unroll
    for (int u = 0; u < 4; u++) {
      float4 v = prow[q*4 + u];
      int c0 = 3 + q*16 + u*4;
      xsm[(c0+0)*68 + pxl] = v.x;
      xsm[(c0+1)*68 + pxl] = v.y;
      xsm[(c0+2)*68 + pxl] = v.z;
      xsm[(c0+3)*68 + pxl] = v.w;
    }
    if (q == 0) {
      const float* xr = xyz + ((size_t)b * NN + j) * 3;
      const int cj = cents_g[bs] & (NN-1);
      const float* ce = xyz + ((size_t)b * NN + cj) * 3;
      xsm[0*68 + pxl] = xr[0] - ce[0];
      xsm[1*68 + pxl] = xr[1] - ce[1];
      xsm[2*68 + pxl] = xr[2] - ce[2];
    }
  }
  __syncthreads();

  // ---- gemm1 (67 -> 64) f32 ----
  float acc[4][4] = {};
  for (int cc = 0; cc < 67; cc++) {
    float4 xv = *(const float4*)&xsm[cc*68 + 4*tr];
    float4 wv = *(const float4*)&wbuf[cc*64 + 4*tc];
    float xa[4] = {xv.x, xv.y, xv.z, xv.w};
    float wa[4] = {wv.x, wv.y, wv.z, wv.w};
    #pragma unroll
    for (int i = 0; i < 4; i++)
      #pragma unroll
      for (int jj = 0; jj < 4; jj++) acc[i][jj] += xa[i]*wa[jj];
  }
  if constexpr (MODE == 1) {
    double s1[4] = {0,0,0,0}, s2[4] = {0,0,0,0};
    #pragma unroll
    for (int jj = 0; jj < 4; jj++) {
      float bb = bsm[4*tc+jj];
      #pragma unroll
      for (int i = 0; i < 4; i++) {
        double yd = (double)(acc[i][jj] + bb);
        s1[jj] += yd; s2[jj] += yd*yd;
      }
    }
    #pragma unroll
    for (int off = 8; off > 0; off >>= 1)
      #pragma unroll
      for (int jj = 0; jj < 4; jj++) {
        s1[jj] += __shfl_down(s1[jj], off, 16);
        s2[jj] += __shfl_down(s2[jj], off, 16);
      }
    if (tr == 0)
      #pragma unroll
      for (int jj = 0; jj < 4; jj++) {
        pout[4*tc+jj]       = s1[jj];
        pout[128 + 4*tc+jj] = s2[jj];
      }
    return;
  }

  __syncthreads();
  #pragma unroll
  for (int jj = 0; jj < 4; jj++) {
    int oc = 4*tc + jj;
    float bb = bsm[oc], sc = sc1m[oc], sh = sh1m[oc];
    float r[4];
    #pragma unroll
    for (int i = 0; i < 4; i++) r[i] = fmaxf((acc[i][jj] + bb)*sc + sh, 0.f);
    *(float4*)&xsm[oc*68 + 4*tr] = make_float4(r[0], r[1], r[2], r[3]);
  }
  for (int ii = t; ii < 4096; ii += 256) {
    int oc = ii & 63, cc = ii >> 6;
    wbuf[cc*64 + oc] = w2[oc*64 + cc];
  }
  if (t < 64) bsm2[t] = b2[t];
  __syncthreads();

  // ---- gemm2 (64 -> 64) f32 ----
  float acc2[4][4] = {};
  for (int cc = 0; cc < 64; cc++) {
    float4 xv = *(const float4*)&xsm[cc*68 + 4*tr];
    float4 wv = *(const float4*)&wbuf[cc*64 + 4*tc];
    float xa[4] = {xv.x, xv.y, xv.z, xv.w};
    float wa[4] = {wv.x, wv.y, wv.z, wv.w};
    #pragma unroll
    for (int i = 0; i < 4; i++)
      #pragma unroll
      for (int jj = 0; jj < 4; jj++) acc2[i][jj] += xa[i]*wa[jj];
  }
  if constexpr (MODE == 2) {
    double s1[4] = {0,0,0,0}, s2[4] = {0,0,0,0};
    #pragma unroll
    for (int jj = 0; jj < 4; jj++) {
      float bb = bsm2[4*tc+jj];
      #pragma unroll
      for (int i = 0; i < 4; i++) {
        double yd = (double)(acc2[i][jj] + bb);
        s1[jj] += yd; s2[jj] += yd*yd;
      }
    }
    #pragma unroll
    for (int off = 8; off > 0; off >>= 1)
      #pragma unroll
      for (int jj = 0; jj < 4; jj++) {
        s1[jj] += __shfl_down(s1[jj], off, 16);
        s2[jj] += __shfl_down(s2[jj], off, 16);
      }
    if (tr == 0)
      #pragma unroll
      for (int jj = 0; jj < 4; jj++) {
        pout[4*tc+jj]       = s1[jj];
        pout[128 + 4*tc+jj] = s2[jj];
      }
    return;
  }

  if constexpr (MODE == 3) {
    __syncthreads();
    #pragma unroll
    for (int jj = 0; jj < 4; jj++) {
      int oc = 4*tc + jj;
      float bb = bsm2[oc], sc = sc2m[oc], sh = sh2m[oc];
      float r[4];
      #pragma unroll
      for (int i = 0; i < 4; i++) r[i] = fmaxf((acc2[i][jj] + bb)*sc + sh, 0.f);
      *(float4*)&xsm[oc*68 + 4*tr] = make_float4(r[0], r[1], r[2], r[3]);
    }
    for (int h = 0; h < 2; h++) {
      for (int ii = t; ii < 4096; ii += 256) {
        int oc = ii & 63, cc = ii >> 6;
        wbuf[cc*64 + oc] = w3[(h*64 + oc)*64 + cc];
      }
      if (t < 64) bsm[t] = b3[h*64 + t];
      __syncthreads();
      float acc3[4][4] = {};
      for (int cc = 0; cc < 64; cc++) {
        float4 xv = *(const float4*)&xsm[cc*68 + 4*tr];
        float4 wv = *(const float4*)&wbuf[cc*64 + 4*tc];
        float xa[4] = {xv.x, xv.y, xv.z, xv.w};
        float wa[4] = {wv.x, wv.y, wv.z, wv.w};
        #pragma unroll
        for (int i = 0; i < 4; i++)
          #pragma unroll
          for (int jj = 0; jj < 4; jj++) acc3[i][jj] += xa[i]*wa[jj];
      }
      double s1[4] = {0,0,0,0}, s2[4] = {0,0,0,0};
      float pmx[4], pmn[4];
      #pragma unroll
      for (int jj = 0; jj < 4; jj++) { pmx[jj] = -3.4e38f; pmn[jj] = 3.4e38f; }
      #pragma unroll
      for (int jj = 0; jj < 4; jj++) {
        float bb = bsm[4*tc+jj];
        #pragma unroll
        for (int i = 0; i < 4; i++) {
          float y = acc3[i][jj] + bb;
          double yd = (double)y;
          s1[jj] += yd; s2[jj] += yd*yd;
          pmx[jj] = fmaxf(pmx[jj], y); pmn[jj] = fminf(pmn[jj], y);
        }
      }
      #pragma unroll
      for (int off = 8; off > 0; off >>= 1)
        #pragma unroll
        for (int jj = 0; jj < 4; jj++) {
          s1[jj] += __shfl_down(s1[jj], off, 16);
          s2[jj] += __shfl_down(s2[jj], off, 16);
        }
      if (tr == 0)
        #pragma unroll
        for (int jj = 0; jj < 4; jj++) {
          pout[h*64 + 4*tc+jj]       = s1[jj];
          pout[128 + h*64 + 4*tc+jj] = s2[jj];
        }
      #pragma unroll
      for (int off = 4; off > 0; off >>= 1)
        #pragma unroll
        for (int jj = 0; jj < 4; jj++) {
          pmx[jj] = fmaxf(pmx[jj], __shfl_down(pmx[jj], off, 8));
          pmn[jj] = fminf(pmn[jj], __shfl_down(pmn[jj], off, 8));
        }
      if ((tr & 7) == 0) {
        int bs = (pb >> 5) + (tr >> 3);
        size_t ob = (size_t)bs*128 + h*64 + 4*tc;
        #pragma unroll
        for (int jj = 0; jj < 4; jj++) {
          pmax[ob + jj] = pmx[jj];
          pmin[ob + jj] = pmn[jj];
        }
      }
      __syncthreads();
    }
  }
}

// ---------------- reduce partials + compute affine -------------------------------
__global__ __launch_bounds__(256) void reduce_finalize_kernel(
    const double* __restrict__ partial,
    const float* __restrict__ g, const float* __restrict__ beta,
    double* __restrict__ aff) {
  __shared__ double sa1[4], sa2[4];
  const int c = blockIdx.x;
  const int t = threadIdx.x;
  double a1 = 0.0, a2 = 0.0;
  for (int blk = t; blk < NBLK; blk += 256) {
    a1 += partial[(size_t)blk*256 + c];
    a2 += partial[(size_t)blk*256 + 128 + c];
  }
  #pragma unroll
  for (int off = 32; off > 0; off >>= 1) {
    a1 += __shfl_down(a1, off);
    a2 += __shfl_down(a2, off);
  }
  const int lane = t & 63, wid = t >> 6;
  if (lane == 0) { sa1[wid] = a1; sa2[wid] = a2; }
  __syncthreads();
  if (t == 0) {
    double s1 = sa1[0] + sa1[1] + sa1[2] + sa1[3];
    double s2 = sa2[0] + sa2[1] + sa2[2] + sa2[3];
    const double invN = 1.0 / (double)NPIX;
    double mean = s1 * invN;
    double var  = s2 * invN - mean*mean;
    var = var > 0.0 ? var : 0.0;
    double r  = 1.0 / sqrt(var + BN_EPS);
    double sc = (double)g[c] * r;
    aff[c]       = sc;
    aff[128 + c] = (double)beta[c] - mean*sc;
  }
}

// ---------------- epilogue: bn3+relu on pooled extremum (monotone trick) ---------
__global__ __launch_bounds__(256) void out_kernel(
    const float* __restrict__ pmax, const float* __restrict__ pmin,
    const double* __restrict__ aff3, float* __restrict__ out_np) {
  int i = blockIdx.x * 256 + threadIdx.x;   // [0, 2097152)
  int oc = i & 127;
  double sc = aff3[oc], sh = aff3[128+oc];
  double v = (sc >= 0.0) ? (double)pmax[i] : (double)pmin[i];
  double y = v*sc + sh;
  out_np[i] = (float)(y > 0.0 ? y : 0.0);
}

// ---------------- sole writer of new_xyz ------------------------------------------
__global__ __launch_bounds__(1024) void write_newxyz_kernel(
    const float* __restrict__ xyz, const int* __restrict__ cents_g,
    float* __restrict__ out) {
  int i = blockIdx.x * 1024 + threadIdx.x;    // [0, 16384)
  int b = i >> 10;
  int j = cents_g[i] & (NN-1);
  const float* src = xyz + ((size_t)b * NN + j) * 3;
  size_t o = (size_t)i * 3;
  out[o+0] = src[0];
  out[o+1] = src[1];
  out[o+2] = src[2];
}

extern "C" void kernel_launch(void* const* d_in, const int* in_sizes, int n_in,
                              void* d_out, int out_size, void* d_ws, size_t ws_size,
                              hipStream_t stream) {
  const float* xyz    = (const float*)d_in[0];
  const float* points = (const float*)d_in[1];
  const float* w1  = (const float*)d_in[2];
  const float* b1  = (const float*)d_in[3];
  const float* g1  = (const float*)d_in[4];
  const float* be1 = (const float*)d_in[5];
  const float* w2  = (const float*)d_in[6];
  const float* b2  = (const float*)d_in[7];
  const float* g2  = (const float*)d_in[8];
  const float* be2 = (const float*)d_in[9];
  const float* w3  = (const float*)d_in[10];
  const float* b3  = (const float*)d_in[11];
  const float* g3  = (const float*)d_in[12];
  const float* be3 = (const float*)d_in[13];

  // workspace ~36 MB (known safe: 86 MB ran clean in R2)
  char* ws = (char*)d_ws;
  double* aff     = (double*)(ws + 8192);      // 768 f64
  int*    cents   = (int*)  (ws + 16384);      // 16384 i32
  int*    idx     = (int*)  (ws + 81920);      // 524288 i32
  float*  pmax    = (float*)(ws + 2179072);    // 2097152 f32
  float*  pmin    = (float*)(ws + 10567680);   // 2097152 f32
  double* partial = (double*)(ws + 18956288);  // 8192*256 f64 = 16 MB
  float* out_xyz = (float*)d_out;                          // f32 new_xyz
  float* out_np  = (float*)d_out + (size_t)NB*NPOINT*3;    // f32 new_points

  fps_kernel        <<<16,   256, 0, stream>>>(xyz, cents);
  ballquery_kernel  <<<4096, 256, 0, stream>>>(xyz, cents, idx);
  fused_pass<1>     <<<NBLK, 256, 0, stream>>>(xyz, points, cents, idx, w1,b1,w2,b2,w3,b3,
                                               aff, aff+256, partial, pmax, pmin);
  reduce_finalize_kernel<<<64, 256, 0, stream>>>(partial, g1, be1, aff);
  fused_pass<2>     <<<NBLK, 256, 0, stream>>>(xyz, points, cents, idx, w1,b1,w2,b2,w3,b3,
                                               aff, aff+256, partial, pmax, pmin);
  reduce_finalize_kernel<<<64, 256, 0, stream>>>(partial, g2, be2, aff+256);
  fused_pass<3>     <<<NBLK, 256, 0, stream>>>(xyz, points, cents, idx, w1,b1,w2,b2,w3,b3,
                                               aff, aff+256, partial, pmax, pmin);
  reduce_finalize_kernel<<<128, 256, 0, stream>>>(partial, g3, be3, aff+512);
  out_kernel        <<<NBLK, 256, 0, stream>>>(pmax, pmin, aff+512, out_np);
  write_newxyz_kernel<<<16, 1024, 0, stream>>>(xyz, cents, out_xyz);
}